// Round 10
// baseline (100.660 us; speedup 1.0000x reference)
//
#include <hip/hip_runtime.h>

#define BATCH 131072

typedef float v2f __attribute__((ext_vector_type(2)));

__device__ __forceinline__ float fast_tanh(float v) {
    float e = __expf(2.0f * v);
    return 1.0f - 2.0f / (e + 1.0f);
}

template <int CTRL>
__device__ __forceinline__ float dppf(float v) {
    return __int_as_float(__builtin_amdgcn_update_dpp(
        0, __float_as_int(v), CTRL, 0xF, 0xF, true));
}
#define DPP_XOR1 0xB1  // quad_perm [1,0,3,2]
#define DPP_XOR2 0x4E  // quad_perm [2,3,0,1]

// ---------------------------------------------------------------------------
// Element-pair packed state: v2f = (elem A, elem B) of ONE amplitude.
// Lane holds amplitudes r = 4m + sub, m = 0..15, sub = lane&3.
// Wire map: w0 = m bit3, w1 = m bit2, w2 = m bit1, w3 = m bit0,
//           w4 = lane bit1 (DPP_XOR2), w5 = lane bit0 (DPP_XOR1).
// All gate coefficients are element-independent -> every pk op does 2 elems.
// ---------------------------------------------------------------------------
template <int MASK>  // in-register RX (wires 0..3: m bits 3..0)
__device__ __forceinline__ void rx_pairs16(v2f* zr, v2f* zi, float c, float s) {
#pragma unroll
    for (int m = 0; m < 16; ++m) {
        if (m & MASK) continue;
        int m1 = m | MASK;
        v2f ar = zr[m], ai = zi[m], br = zr[m1], bi = zi[m1];
        zr[m]  = c * ar + s * bi;
        zi[m]  = c * ai - s * br;
        zr[m1] = c * br + s * ai;
        zi[m1] = c * bi - s * ar;
    }
}

template <int CTRL>  // cross-lane RX (wires 4,5)
__device__ __forceinline__ void rx_exch16(v2f* zr, v2f* zi, float c, float s) {
#pragma unroll
    for (int m = 0; m < 16; ++m) {
        v2f pr, pi;
        pr.x = dppf<CTRL>(zr[m].x);
        pr.y = dppf<CTRL>(zr[m].y);
        pi.x = dppf<CTRL>(zi[m].x);
        pi.y = dppf<CTRL>(zi[m].y);
        v2f mr = zr[m], mi = zi[m];
        zr[m] = c * mr + s * pi;
        zi[m] = c * mi - s * pr;
    }
}

// wires 1..5 + diagonal of one block (wire 0 handled by caller)
__device__ __forceinline__ void enc_tail16(v2f* zr, v2f* zi, const float* rx,
                                           const float* sDblk, int sub) {
    rx_pairs16<4>(zr, zi, rx[2], rx[3]);   // wire 1: m bit2
    rx_pairs16<2>(zr, zi, rx[4], rx[5]);   // wire 2: m bit1
    rx_pairs16<1>(zr, zi, rx[6], rx[7]);   // wire 3: m bit0
    rx_exch16<DPP_XOR2>(zr, zi, rx[8], rx[9]);    // wire 4: lane bit1
    rx_exch16<DPP_XOR1>(zr, zi, rx[10], rx[11]);  // wire 5: lane bit0
    const float2* dp = (const float2*)sDblk;
#pragma unroll
    for (int m = 0; m < 16; ++m) {
        float2 d = dp[m * 4 + sub];   // (Dr, Di) for r=4m+sub; quad-broadcast
        v2f orr = zr[m], oi = zi[m];
        zr[m] = d.x * orr - d.y * oi;
        zi[m] = d.x * oi + d.y * orr;
    }
}

// ---------------------------------------------------------------------------
// Fused kernel: each block preps params once (wave-specialized, 3 barriers),
// then processes 128 batch elements: lane-quad q holds elems (bA, bA+64)
// packed in v2f halves. Grid = BATCH/128 = 1024 blocks.
//
// LDS: gt[144] | Sr/Si[256] (3-col butterfly) | sA[36] | sRx[36]
//      sW2[512] ([64][8]: 6W+bias+pad row-major) | sB[544] (swizzled)
//      sD2[256] (per block bb: (m*4+sub)*2 = Dr,Di)
// ---------------------------------------------------------------------------
__global__ __launch_bounds__(256, 4) void qae_fused(const float* __restrict__ x,
                                                    const float* __restrict__ Wp,
                                                    const float* __restrict__ bp,
                                                    const float* __restrict__ enc_w,
                                                    const float* __restrict__ dec_w,
                                                    float* __restrict__ out) {
    __shared__ __align__(16) float gt[144];
    __shared__ __align__(16) float Sr[256];
    __shared__ __align__(16) float Si[256];
    __shared__ float sA[36];
    __shared__ float sRx[36];
    __shared__ __align__(16) float sW2[512];
    __shared__ __align__(16) float sB[544];
    __shared__ __align__(16) float sD2[256];

    const int t = threadIdx.x;
    const int bl = t >> 2;
    const int sub = t & 3;

    const size_t bA = (size_t)blockIdx.x * 128 + bl;
    const size_t bB = bA + 64;
    // hoist x loads for both elements: latency hides under prep
    const float* xpA = x + bA * 6;
    const float* xpB = x + bB * 6;
    float2 a01 = *(const float2*)(xpA);
    float2 a23 = *(const float2*)(xpA + 2);
    float2 a45 = *(const float2*)(xpA + 4);
    float2 b01 = *(const float2*)(xpB);
    float2 b23 = *(const float2*)(xpB + 2);
    float2 b45 = *(const float2*)(xpB + 4);

    if (t < 64) {
        // ===== wave 0: decoder butterfly (3-col), barrier-free in-wave =====
        if (t < 18) {
            float tx = dec_w[t * 3 + 0];
            float tz = dec_w[t * 3 + 1];
            float c = cosf(0.5f * tx), s = sinf(0.5f * tx);
            float ch = cosf(0.5f * tz), sh = sinf(0.5f * tz);
            gt[t * 8 + 0] = c * ch;  gt[t * 8 + 1] = -c * sh;
            gt[t * 8 + 2] = -s * sh; gt[t * 8 + 3] = -s * ch;
            gt[t * 8 + 4] = s * sh;  gt[t * 8 + 5] = -s * ch;
            gt[t * 8 + 6] = c * ch;  gt[t * 8 + 7] = c * sh;
            float etx = enc_w[t * 3 + 0];
            float ec = cosf(0.5f * etx), es = sinf(0.5f * etx);
            if (t >= 12) {  // block 2 folded into observable
                sRx[2 * t] = ec * ec - es * es;   // cos(tx)
                sRx[2 * t + 1] = 4.0f * ec * es;  // 2*sin(tx)
            } else {
                sRx[2 * t] = ec;
                sRx[2 * t + 1] = es;
            }
        }
#pragma unroll
        for (int q = 0; q < 4; ++q) {
            int f = t + 64 * q;
            int r = f >> 2, c = f & 3;
            Sr[f] = (r == c && c < 3) ? 1.0f : 0.0f;
            Si[f] = 0.0f;
        }
        const int cl = t & 3;
        const int pq = t >> 2;   // 0..15
        for (int bb = 0; bb < 3; ++bb) {
            for (int w = 0; w < 6; ++w) {
                int g = bb * 6 + w;
                int p = 5 - w;
                float u00r = gt[g * 8 + 0], u00i = gt[g * 8 + 1];
                float u01r = gt[g * 8 + 2], u01i = gt[g * 8 + 3];
                float u10r = gt[g * 8 + 4], u10i = gt[g * 8 + 5];
                float u11r = gt[g * 8 + 6], u11i = gt[g * 8 + 7];
#pragma unroll
                for (int h = 0; h < 2; ++h) {
                    int pp = pq + 16 * h;
                    int r0 = ((pp >> p) << (p + 1)) | (pp & ((1 << p) - 1));
                    int r1 = r0 | (1 << p);
                    float ar = Sr[r0 * 4 + cl], ai = Si[r0 * 4 + cl];
                    float br = Sr[r1 * 4 + cl], bi = Si[r1 * 4 + cl];
                    Sr[r0 * 4 + cl] = u00r * ar - u00i * ai + u01r * br - u01i * bi;
                    Si[r0 * 4 + cl] = u00r * ai + u00i * ar + u01r * bi + u01i * br;
                    Sr[r1 * 4 + cl] = u10r * ar - u10i * ai + u11r * br - u11i * bi;
                    Si[r1 * 4 + cl] = u10r * ai + u10i * ar + u11r * bi + u11i * br;
                }
            }
#pragma unroll
            for (int q = 0; q < 4; ++q) {
                int f = t + 64 * q;
                int r = f >> 2;
                if (__popc(r & (r >> 1)) & 1) {
                    Sr[f] = -Sr[f];
                    Si[f] = -Si[f];
                }
            }
        }
    } else if (t < 192) {
        // ===== waves 1-2: stage sW2 [64][8] = 6W + bias + pad =============
#pragma unroll
        for (int q = 0; q < 4; ++q) {
            int f = (t - 64) + 128 * q;
            int row = f >> 3, e = f & 7;
            float val;
            if (e < 6)       val = Wp[row * 6 + e];
            else if (e == 6) val = bp[row];
            else             val = 0.0f;
            sW2[f] = val;
        }
    } else {
        // ===== wave 3: sD2 enc diag trig; (m*4+sub)*2 = (Dr,Di), r=4m+sub ==
#pragma unroll
        for (int q = 0; q < 2; ++q) {
            int idx = (t - 192) + 64 * q;
            int bb = idx >> 6, r = idx & 63;
            float phi = 0.0f;
            for (int k = 0; k < 6; ++k) {
                float tz = enc_w[(bb * 6 + k) * 3 + 1];
                phi += ((r >> (5 - k)) & 1) ? 0.5f * tz : -0.5f * tz;
            }
            float sgn = (__popc(r & (r >> 1)) & 1) ? -1.0f : 1.0f;
            int m = r >> 2, su = r & 3;
            int base = bb * 128 + (m * 4 + su) * 2;
            sD2[base]     = sgn * cosf(phi);
            sD2[base + 1] = sgn * sinf(phi);
        }
    }
    __syncthreads();

    // folded decoder quadratic forms A' (6 coeffs per output k)
    if (t < 36) {
        int k = t / 6, i = t % 6;
        int d = (i < 3) ? i : ((i == 5) ? 1 : 0);
        int e = (i < 3) ? i : ((i == 3) ? 1 : 2);
        float acc = 0.0f;
        for (int r = 0; r < 64; ++r) {
            float term = Sr[r * 4 + d] * Sr[r * 4 + e] + Si[r * 4 + d] * Si[r * 4 + e];
            acc += ((r >> (5 - k)) & 1) ? -term : term;
        }
        if (i >= 3) acc *= 2.0f;
        sA[t] = acc;
    }
    __syncthreads();

    // sB: B[row] = W[row,:]·A', swizzled row r at 8r + (r>>4)*4
    if (t < 64) {
        float w0 = Wp[t * 6 + 0], w1 = Wp[t * 6 + 1], w2 = Wp[t * 6 + 2];
        float w3 = Wp[t * 6 + 3], w4 = Wp[t * 6 + 4], w5 = Wp[t * 6 + 5];
        int basep = 8 * t + ((t >> 4) << 2);
#pragma unroll
        for (int i = 0; i < 6; ++i) {
            float acc = w0 * sA[0 * 6 + i] + w1 * sA[1 * 6 + i] + w2 * sA[2 * 6 + i]
                      + w3 * sA[3 * 6 + i] + w4 * sA[4 * 6 + i] + w5 * sA[5 * 6 + i];
            sB[basep + i] = acc;
        }
        sB[basep + 6] = bp[t];
        sB[basep + 7] = 0.0f;
    }
    __syncthreads();

    // ================= main compute: 2 elements in v2f halves ==============
    v2f xv[6];
    xv[0] = (v2f){a01.x, b01.x}; xv[1] = (v2f){a01.y, b01.y};
    xv[2] = (v2f){a23.x, b23.x}; xv[3] = (v2f){a23.y, b23.y};
    xv[4] = (v2f){a45.x, b45.x}; xv[5] = (v2f){a45.y, b45.y};

    // h = tanh(xW^T+b): lane does rows r = 4m+sub for both elements.
    v2f zr[16], zi[16];
    v2f S2 = {0.0f, 0.0f};
#pragma unroll
    for (int m = 0; m < 16; ++m) {
        const float* wb = &sW2[(4 * m + sub) * 8];
        float4 c0 = *(const float4*)wb;        // w0..w3
        float4 c1 = *(const float4*)(wb + 4);  // w4, w5, bias, pad
        v2f a = {c1.z, c1.z};
        a += c0.x * xv[0];
        a += c0.y * xv[1];
        a += c0.z * xv[2];
        a += c0.w * xv[3];
        a += c1.x * xv[4];
        a += c1.y * xv[5];
        v2f th = {fast_tanh(a.x), fast_tanh(a.y)};
        zr[m] = th;
        S2 += th * th;
    }
    S2.x += dppf<DPP_XOR1>(S2.x); S2.x += dppf<DPP_XOR2>(S2.x);
    S2.y += dppf<DPP_XOR1>(S2.y); S2.y += dppf<DPP_XOR2>(S2.y);
    v2f invS = {__builtin_amdgcn_rcpf(S2.x), __builtin_amdgcn_rcpf(S2.y)};

    // ---- block 0: wire 0 (m bit3) specialized for real input (zi==0) ----
    {
        const float* rx = sRx;
        float c = rx[0], s = rx[1];
#pragma unroll
        for (int m = 0; m < 8; ++m) {
            v2f a = zr[m], b2 = zr[m + 8];
            zr[m]     = c * a;
            zi[m]     = -s * b2;
            zr[m + 8] = c * b2;
            zi[m + 8] = -s * a;
        }
        enc_tail16(zr, zi, rx, sD2, sub);
    }
    // ---- block 1: generic ----
    {
        const float* rx = sRx + 12;
        rx_pairs16<8>(zr, zi, rx[0], rx[1]);
        enc_tail16(zr, zi, rx, sD2 + 128, sub);
    }

    // latent via folded block-2 observable (both elements at once):
    //   latent_k = (cos(tx_k)*<Z_k> + sin(tx_k)*<Y_k>)/S
    // signs/pairs: k=0 -> m bit3, k=1 -> m bit2, k=2 -> m bit1
    v2f L0 = {0, 0}, L1 = {0, 0}, L2 = {0, 0};
#pragma unroll
    for (int m = 0; m < 16; ++m) {
        v2f p = zr[m] * zr[m] + zi[m] * zi[m];
        L0 += (m & 8) ? -p : p;
        L1 += (m & 4) ? -p : p;
        L2 += (m & 2) ? -p : p;
    }
    v2f Y0 = {0, 0}, Y1 = {0, 0}, Y2 = {0, 0};
#pragma unroll
    for (int m = 0; m < 8; ++m)
        Y0 += zr[m] * zi[m | 8] - zi[m] * zr[m | 8];
#pragma unroll
    for (int m = 0; m < 16; ++m) {
        if (!(m & 4)) Y1 += zr[m] * zi[m | 4] - zi[m] * zr[m | 4];
    }
#pragma unroll
    for (int m = 0; m < 16; ++m) {
        if (!(m & 2)) Y2 += zr[m] * zi[m | 2] - zi[m] * zr[m | 2];
    }

    const float* p2 = sRx + 24;
    v2f t0 = p2[0] * L0 + p2[1] * Y0;
    v2f t1 = p2[2] * L1 + p2[3] * Y1;
    v2f t2 = p2[4] * L2 + p2[5] * Y2;
    t0.x += dppf<DPP_XOR1>(t0.x); t0.x += dppf<DPP_XOR2>(t0.x);
    t0.y += dppf<DPP_XOR1>(t0.y); t0.y += dppf<DPP_XOR2>(t0.y);
    t1.x += dppf<DPP_XOR1>(t1.x); t1.x += dppf<DPP_XOR2>(t1.x);
    t1.y += dppf<DPP_XOR1>(t1.y); t1.y += dppf<DPP_XOR2>(t1.y);
    t2.x += dppf<DPP_XOR1>(t2.x); t2.x += dppf<DPP_XOR2>(t2.x);
    t2.y += dppf<DPP_XOR1>(t2.y); t2.y += dppf<DPP_XOR2>(t2.y);
    v2f l0 = t0 * invS, l1 = t1 * invS, l2 = t2 * invS;

    // latent out for both elements
    if (sub == 0) {
        size_t loA = (size_t)BATCH * 64 + bA * 3;
        size_t loB = (size_t)BATCH * 64 + bB * 3;
        out[loA]     = l0.x;
        out[loA + 1] = l1.x;
        out[loA + 2] = l2.x;
        out[loB]     = l0.y;
        out[loB + 1] = l1.y;
        out[loB + 2] = l2.y;
    }

    // q-hat = q * inv(l^T l) (per element, packed)
    v2f q0 = l0 * l0, q1 = l1 * l1, q2 = l2 * l2;
    v2f r2 = q0 + q1 + q2;
    v2f invr2 = {__builtin_amdgcn_rcpf(r2.x), __builtin_amdgcn_rcpf(r2.y)};
    v2f qh0 = q0 * invr2, qh1 = q1 * invr2, qh2 = q2 * invr2;
    v2f qh3 = (l0 * l1) * invr2, qh4 = (l0 * l2) * invr2, qh5 = (l1 * l2) * invr2;

    // reconstructed = tanh(B q-hat + b); thread covers rows 16sub..16sub+15
    // for BOTH elements (B coeffs scalar -> pk ops serve both).
    const float* bB2 = &sB[132 * sub];
    const size_t obA = bA * 64 + 16 * sub;
    const size_t obB = bB * 64 + 16 * sub;
#pragma unroll
    for (int ch = 0; ch < 4; ++ch) {
        float vA[4], vB[4];
#pragma unroll
        for (int r = 0; r < 4; ++r) {
            int qq = ch * 4 + r;
            float4 u0 = *(const float4*)&bB2[8 * qq];
            float4 u1 = *(const float4*)&bB2[8 * qq + 4];  // B4,B5,bias,pad
            v2f acc = {u1.z, u1.z};
            acc += u0.x * qh0;
            acc += u0.y * qh1;
            acc += u0.z * qh2;
            acc += u0.w * qh3;
            acc += u1.x * qh4;
            acc += u1.y * qh5;
            vA[r] = fast_tanh(acc.x);
            vB[r] = fast_tanh(acc.y);
        }
        float4 oA = {vA[0], vA[1], vA[2], vA[3]};
        float4 oB = {vB[0], vB[1], vB[2], vB[3]};
        *(float4*)&out[obA + ch * 4] = oA;
        *(float4*)&out[obB + ch * 4] = oB;
    }
}

extern "C" void kernel_launch(void* const* d_in, const int* in_sizes, int n_in,
                              void* d_out, int out_size, void* d_ws, size_t ws_size,
                              hipStream_t stream) {
    const float* x   = (const float*)d_in[0];
    const float* Wp  = (const float*)d_in[1];
    const float* bpv = (const float*)d_in[2];
    const float* enc = (const float*)d_in[3];
    const float* dec = (const float*)d_in[4];
    float* out = (float*)d_out;

    qae_fused<<<BATCH / 128, 256, 0, stream>>>(x, Wp, bpv, enc, dec, out);
}